// Round 5
// baseline (168.606 us; speedup 1.0000x reference)
//
#include <hip/hip_runtime.h>
#include <math.h>

#define N_S 32
#define C_DIM 3
#define F_DIM 3277
#define T_DIM 256
#define FT (F_DIM * T_DIM)        /* 838912  */
#define CFT (F_DIM * T_DIM * C_DIM) /* 2516736 */
#define CFT4 (CFT / 4)            /* 629184 float4 per sample */
#define P4 (FT / 4)               /* 209728 float4 per (n,c) plane */
#define FC_IDX 1084
#define N_NOISE 2949
#define NQ (3 * N_NOISE * 64)     /* 566208 noise float4s per sample */
#define TH0 104832                /* 1638*64 */
#define TH1 293568                /* TH0 + 188736 */
#define TH2 482304                /* TH0 + 2*188736 */
#define SKIP4 20992               /* 328*64 */
#define NB 64                     /* noise blocks per sample */
#define NPART NB
#define PLANES (N_S * C_DIM)      /* 96 */

struct WS {
  float              noise_partial[N_S][256];
  int                mid[N_S];
  int                hb[N_S];
  unsigned long long tbits[N_S][4];
};

// ---- K1: noise partials — fill-clone flat ascending read stream -------------
// Block (b, n) grid-strides the flat noise-index space q of sample n.
// addr = q + SKIP4 * (#thresholds passed) maps noise-q -> plane float4 index.
__global__ __launch_bounds__(256) void k_noise(const float4* __restrict__ xv,
                                               WS* __restrict__ ws) {
  int n = blockIdx.y;
  int b = blockIdx.x;
  const float4* smp = xv + (size_t)n * CFT4;
  float acc = 0.f;
  #pragma unroll 4
  for (int q = b * 256 + (int)threadIdx.x; q < NQ; q += NB * 256) {
    int add = 0;
    if (q >= TH0) add += SKIP4;
    if (q >= TH1) add += SKIP4;
    if (q >= TH2) add += SKIP4;
    float4 v = smp[q + add];
    acc += fabsf(v.x) + fabsf(v.y) + fabsf(v.z) + fabsf(v.w);
  }
  for (int off = 32; off; off >>= 1) acc += __shfl_down(acc, off);
  __shared__ double wsum[4];
  int w = threadIdx.x >> 6, lane = threadIdx.x & 63;
  if (lane == 0) wsum[w] = (double)acc;
  __syncthreads();
  if (threadIdx.x == 0) {
    ws->noise_partial[n][b] = (float)(wsum[0] + wsum[1] + wsum[2] + wsum[3]);
  }
}

// ---- K2: per-sample stats — verbatim except NPART=64 partials ---------------
__global__ __launch_bounds__(256) void k_stats(const float* __restrict__ x,
                                               WS* __restrict__ ws) {
  int n = blockIdx.x;
  int t = threadIdx.x;
  const float* p = x + (size_t)n * CFT + (size_t)FC_IDX * T_DIM + t;
  float m = fabsf(p[0]) + fabsf(p[FT]) + fabsf(p[2 * FT]);

  __shared__ float  smag[256];
  __shared__ float  sv[256];
  __shared__ int    si[256];
  __shared__ double sd[256];
  smag[t] = m; sv[t] = m; si[t] = t;
  sd[t] = (t < NPART) ? (double)ws->noise_partial[n][t] : 0.0;
  __syncthreads();
  for (int s = 128; s > 0; s >>= 1) {
    if (t < s) {
      if (sv[t + s] > sv[t] || (sv[t + s] == sv[t] && si[t + s] < si[t])) {
        sv[t] = sv[t + s]; si[t] = si[t + s];
      }
      sd[t] += sd[t + s];
    }
    __syncthreads();
  }
  if (t == 0) {
    int mid = si[0];
    double noise_d = sd[0] / ((double)N_NOISE * (double)T_DIM);
    int lo = mid - 8; if (lo < 0) lo = 0;
    int hi = mid + 8; if (hi > T_DIM) hi = T_DIM;
    double sig_d = 0.0;
    for (int tt = lo; tt < hi; ++tt) sig_d += (double)smag[tt];
    float sig = (float)sig_d, noise = (float)noise_d;
    float d   = sig - noise;
    float snr = 10.0f * log10f((d * d) / (noise * noise));
    float hbf = 12.5f * (snr - 20.0f) + 27.0f;
    int hb = (int)truncf(hbf);
    if (hb < 8) hb = 8;
    ws->mid[n] = mid;
    ws->hb[n]  = hb;
    int wlo = mid - 8, whi = mid + 8;
    #pragma unroll
    for (int wd = 0; wd < 4; ++wd) {
      int base = wd * 64;
      int a = wlo - base; if (a < 0) a = 0;
      int b = whi - base; if (b > 64) b = 64;
      unsigned long long msk = 0ULL;
      if (b > a) {
        unsigned long long hiM = (b >= 64) ? ~0ULL : ((1ULL << b) - 1ULL);
        unsigned long long loM = (1ULL << a) - 1ULL;
        msk = hiM & ~loM;
      }
      ws->tbits[n][wd] = msk;
    }
  }
}

// ---- K3: full-output write, one wave per freq row — VERBATIM from round 4 ---
__global__ __launch_bounds__(256) void k_out(const float4* __restrict__ xv,
                                             float4* __restrict__ ov,
                                             const WS* __restrict__ ws) {
  int w    = threadIdx.x >> 6;        // wave 0..3
  int lane = threadIdx.x & 63;        // lane = float4 index within the row
  int f    = blockIdx.x * 4 + w;
  if (f >= F_DIM) return;             // only block 819, waves 1..3

  int word_idx = lane >> 4;           // which 64-bit tbits word
  unsigned long long m = 0ULL;
  #pragma unroll 4
  for (int n = 0; n < N_S; ++n) {
    int hb = ws->hb[n];
    if (f >= FC_IDX - hb && f < FC_IDX + hb) m |= ws->tbits[n][word_idx];
  }
  unsigned bits = (unsigned)(m >> ((lane & 15) * 4)) & 0xFu;

  const float4* xr  = xv + (size_t)f * 64 + lane;
  float4*       orw = ov + (size_t)f * 64 + lane;
  int p0 = blockIdx.y * (PLANES / 4);
  #pragma unroll 4
  for (int p = p0; p < p0 + PLANES / 4; ++p) {
    size_t off = (size_t)p * P4;
    float4 r = {0.f, 0.f, 0.f, 0.f};
    if (bits) {
      float4 v = xr[off];
      if (bits & 1u) r.x = v.x;
      if (bits & 2u) r.y = v.y;
      if (bits & 4u) r.z = v.z;
      if (bits & 8u) r.w = v.w;
    }
    orw[off] = r;
  }
}

extern "C" void kernel_launch(void* const* d_in, const int* in_sizes, int n_in,
                              void* d_out, int out_size, void* d_ws, size_t ws_size,
                              hipStream_t stream) {
  const float* x   = (const float*)d_in[0];
  float*       out = (float*)d_out;
  WS*          ws  = (WS*)d_ws;

  dim3 gn(NB, N_S);
  k_noise<<<gn, 256, 0, stream>>>((const float4*)x, ws);
  k_stats<<<N_S, 256, 0, stream>>>(x, ws);
  dim3 g((F_DIM + 3) / 4, 4);
  k_out <<<g, 256, 0, stream>>>((const float4*)x, (float4*)out, ws);
}